// Round 1
// baseline (7229.321 us; speedup 1.0000x reference)
//
#include <hip/hip_runtime.h>
#include <cstdint>
#include <cstddef>

#define D_IN   2048
#define D_SAE  16384
#define KTOP   100
#define BATCH  8192

typedef unsigned short u16;
typedef unsigned int   u32;
typedef _Float16 f16x8 __attribute__((ext_vector_type(8)));
typedef float    f32x4 __attribute__((ext_vector_type(4)));

// ---------------- split conversion: x - b_dec -> f16 hi/lo ----------------
__global__ __launch_bounds__(256)
void convert_x_kernel(const float* __restrict__ x, const float* __restrict__ b_dec,
                      u16* __restrict__ x_hi, u16* __restrict__ x_lo) {
  size_t gid = (size_t)blockIdx.x * blockDim.x + threadIdx.x;  // one float4
  size_t base = gid * 4;
  const float4 xv = *(const float4*)(x + base);
  const float4 bd = *(const float4*)(b_dec + (base & (D_IN - 1)));
  float t[4] = {xv.x - bd.x, xv.y - bd.y, xv.z - bd.z, xv.w - bd.w};
  u32 hpack[2], lpack[2];
  u16 h[4], l[4];
#pragma unroll
  for (int i = 0; i < 4; ++i) {
    _Float16 hi = (_Float16)t[i];
    _Float16 lo = (_Float16)(t[i] - (float)hi);
    h[i] = __builtin_bit_cast(u16, hi);
    l[i] = __builtin_bit_cast(u16, lo);
  }
  hpack[0] = (u32)h[0] | ((u32)h[1] << 16); hpack[1] = (u32)h[2] | ((u32)h[3] << 16);
  lpack[0] = (u32)l[0] | ((u32)l[1] << 16); lpack[1] = (u32)l[2] | ((u32)l[3] << 16);
  *(uint2*)(x_hi + base) = make_uint2(hpack[0], hpack[1]);
  *(uint2*)(x_lo + base) = make_uint2(lpack[0], lpack[1]);
}

// ------------- W_enc [K][N] fp32 -> Wt [N][K] f16 hi/lo (transpose) -------------
__global__ __launch_bounds__(256)
void convert_w_kernel(const float* __restrict__ W, u16* __restrict__ wh, u16* __restrict__ wl) {
  __shared__ float tile[32][33];
  const int tx = threadIdx.x, ty = threadIdx.y;       // 32 x 8
  const int n0 = blockIdx.x * 32, k0 = blockIdx.y * 32;
#pragma unroll
  for (int i = 0; i < 4; ++i)
    tile[ty + 8 * i][tx] = W[(size_t)(k0 + ty + 8 * i) * D_SAE + n0 + tx];
  __syncthreads();
#pragma unroll
  for (int i = 0; i < 4; ++i) {
    int nl = ty + 8 * i;
    float v = tile[tx][nl];
    _Float16 hi = (_Float16)v;
    _Float16 lo = (_Float16)(v - (float)hi);
    size_t o = (size_t)(n0 + nl) * D_IN + k0 + tx;
    wh[o] = __builtin_bit_cast(u16, hi);
    wl[o] = __builtin_bit_cast(u16, lo);
  }
}

// ---------------- encode GEMM: pre = relu(x @ W_enc + b_enc) ----------------
// 128x128 tile, BK=32, 4 waves (2x2), f16 split: hi*hi + hi*lo + lo*hi.
// LDS 32 KB single-buffered, register-prefetched staging; 16B-slot XOR swizzle.
__device__ __forceinline__ int lds_off(int mat, int row, int slot) {
  int p = slot ^ ((row >> 1) & 3);
  return mat * 8192 + row * 64 + p * 16;
}

__global__ __launch_bounds__(256, 2)
void encode_gemm_kernel(const u16* __restrict__ x_hi, const u16* __restrict__ x_lo,
                        const u16* __restrict__ w_hi, const u16* __restrict__ w_lo,
                        const float* __restrict__ b_enc,
                        float* __restrict__ pre, int row0) {
  __shared__ char smem[32768] __attribute__((aligned(16)));
  const int tid = threadIdx.x;
  const int lane = tid & 63, wid = tid >> 6;
  const int wr = wid >> 1, wc = wid & 1;
  const int fr = lane & 15, fs = lane >> 4;

  const int mBlk = blockIdx.y * 128;   // chunk-local row base
  const int nBlk = blockIdx.x * 128;

  // staging: 512 16B-chunks per matrix; thread handles chunk ids {tid, tid+256}
  const int r0 = tid >> 2, s0 = tid & 3;
  const int r1 = r0 + 64;  // (tid+256)>>2 ; slot unchanged
  const size_t aOff0 = (size_t)(row0 + mBlk + r0) * D_IN + s0 * 8;
  const size_t aOff1 = (size_t)(row0 + mBlk + r1) * D_IN + s0 * 8;
  const size_t bOff0 = (size_t)(nBlk + r0) * D_IN + s0 * 8;
  const size_t bOff1 = (size_t)(nBlk + r1) * D_IN + s0 * 8;

  int wAddr[8];
  wAddr[0] = lds_off(0, r0, s0); wAddr[1] = lds_off(0, r1, s0);
  wAddr[2] = lds_off(1, r0, s0); wAddr[3] = lds_off(1, r1, s0);
  wAddr[4] = lds_off(2, r0, s0); wAddr[5] = lds_off(2, r1, s0);
  wAddr[6] = lds_off(3, r0, s0); wAddr[7] = lds_off(3, r1, s0);

  int aAddrH[4], aAddrL[4], bAddrH[4], bAddrL[4];
#pragma unroll
  for (int m = 0; m < 4; ++m) {
    int r = wr * 64 + m * 16 + fr;
    aAddrH[m] = lds_off(0, r, fs);
    aAddrL[m] = lds_off(1, r, fs);
  }
#pragma unroll
  for (int n = 0; n < 4; ++n) {
    int r = wc * 64 + n * 16 + fr;
    bAddrH[n] = lds_off(2, r, fs);
    bAddrL[n] = lds_off(3, r, fs);
  }

  f32x4 acc[4][4] = {};
  uint4 st[8];

  auto load_stage = [&](int kt) {
    size_t ko = (size_t)kt * 32;
    st[0] = *(const uint4*)(x_hi + aOff0 + ko);
    st[1] = *(const uint4*)(x_hi + aOff1 + ko);
    st[2] = *(const uint4*)(x_lo + aOff0 + ko);
    st[3] = *(const uint4*)(x_lo + aOff1 + ko);
    st[4] = *(const uint4*)(w_hi + bOff0 + ko);
    st[5] = *(const uint4*)(w_hi + bOff1 + ko);
    st[6] = *(const uint4*)(w_lo + bOff0 + ko);
    st[7] = *(const uint4*)(w_lo + bOff1 + ko);
  };

  load_stage(0);
  for (int kt = 0; kt < D_IN / 32; ++kt) {
    __syncthreads();   // all waves done reading LDS from previous step
#pragma unroll
    for (int i = 0; i < 8; ++i) *(uint4*)(smem + wAddr[i]) = st[i];
    __syncthreads();   // staging visible
    if (kt < D_IN / 32 - 1) load_stage(kt + 1);   // overlap HBM with compute

    f16x8 ah[4], al[4], bh[4], bl[4];
#pragma unroll
    for (int m = 0; m < 4; ++m) {
      ah[m] = *(const f16x8*)(smem + aAddrH[m]);
      al[m] = *(const f16x8*)(smem + aAddrL[m]);
    }
#pragma unroll
    for (int n = 0; n < 4; ++n) {
      bh[n] = *(const f16x8*)(smem + bAddrH[n]);
      bl[n] = *(const f16x8*)(smem + bAddrL[n]);
    }
#pragma unroll
    for (int m = 0; m < 4; ++m)
#pragma unroll
      for (int n = 0; n < 4; ++n) {
        acc[m][n] = __builtin_amdgcn_mfma_f32_16x16x32_f16(ah[m], bh[n], acc[m][n], 0, 0, 0);
        acc[m][n] = __builtin_amdgcn_mfma_f32_16x16x32_f16(ah[m], bl[n], acc[m][n], 0, 0, 0);
        acc[m][n] = __builtin_amdgcn_mfma_f32_16x16x32_f16(al[m], bh[n], acc[m][n], 0, 0, 0);
      }
  }

  // epilogue: + b_enc, relu, store chunk-local pre
#pragma unroll
  for (int n = 0; n < 4; ++n) {
    int col = nBlk + wc * 64 + n * 16 + fr;
    float be = b_enc[col];
#pragma unroll
    for (int m = 0; m < 4; ++m) {
      int rowl = mBlk + wr * 64 + m * 16 + fs * 4;
#pragma unroll
      for (int j = 0; j < 4; ++j) {
        float v = acc[m][n][j] + be;
        v = v > 0.f ? v : 0.f;
        pre[(size_t)(rowl + j) * D_SAE + col] = v;
      }
    }
  }
}

// ---------------- top-k: per-row 256 threads, values in VGPRs ----------------
__global__ __launch_bounds__(256)
void topk_kernel(const float* __restrict__ pre, float* __restrict__ tvals,
                 int* __restrict__ tidx, int row0) {
  const int row = blockIdx.x;                       // chunk-local
  const int tid = threadIdx.x;
  const int lane = tid & 63, wid = tid >> 6;
  const float* rp = pre + (size_t)row * D_SAE;
  uint4 u[16];
#pragma unroll
  for (int j = 0; j < 16; ++j)
    u[j] = *(const uint4*)(rp + tid * 4 + j * 1024);

  __shared__ int red[4];
  __shared__ int cnt;

  // binary search max thr with count(>= thr) >= KTOP (uint order == float order, vals >= 0)
  u32 thr = 0;
  for (int b = 30; b >= 0; --b) {
    u32 cand = thr | (1u << b);
    int c = 0;
#pragma unroll
    for (int j = 0; j < 16; ++j)
      c += (u[j].x >= cand) + (u[j].y >= cand) + (u[j].z >= cand) + (u[j].w >= cand);
#pragma unroll
    for (int off = 32; off > 0; off >>= 1) c += __shfl_down(c, off);
    if (lane == 0) red[wid] = c;
    __syncthreads();
    int tot = red[0] + red[1] + red[2] + red[3];
    if (tot >= KTOP) thr = cand;
    __syncthreads();
  }

  if (tid == 0) cnt = 0;
  __syncthreads();
  const int rowg = row0 + row;
  float* tv = tvals + (size_t)rowg * KTOP;
  int*   ti = tidx  + (size_t)rowg * KTOP;
  // pass 1: strictly greater (guaranteed <= KTOP-1 of these)
#pragma unroll
  for (int j = 0; j < 16; ++j) {
    u32 vv[4] = {u[j].x, u[j].y, u[j].z, u[j].w};
#pragma unroll
    for (int q = 0; q < 4; ++q) {
      if (vv[q] > thr) {
        int p = atomicAdd(&cnt, 1);
        if (p < KTOP) { tv[p] = __uint_as_float(vv[q]); ti[p] = tid * 4 + j * 1024 + q; }
      }
    }
  }
  __syncthreads();
  // pass 2: equal to threshold fills the remainder
#pragma unroll
  for (int j = 0; j < 16; ++j) {
    u32 vv[4] = {u[j].x, u[j].y, u[j].z, u[j].w};
#pragma unroll
    for (int q = 0; q < 4; ++q) {
      if (vv[q] == thr) {
        int p = atomicAdd(&cnt, 1);
        if (p < KTOP) { tv[p] = __uint_as_float(vv[q]); ti[p] = tid * 4 + j * 1024 + q; }
      }
    }
  }
}

// ---------------- decode: x_hat = sum_k val*W_dec[idx,:] + b_dec ----------------
__global__ __launch_bounds__(256)
void decode_kernel(const float* __restrict__ tvals, const int* __restrict__ tidx,
                   const float* __restrict__ Wd, const float* __restrict__ b_dec,
                   float* __restrict__ out) {
  const int row = blockIdx.x;
  const int tid = threadIdx.x;
  __shared__ float sv[KTOP];
  __shared__ int   si[KTOP];
  if (tid < KTOP) {
    sv[tid] = tvals[(size_t)row * KTOP + tid];
    si[tid] = tidx[(size_t)row * KTOP + tid];
  }
  __syncthreads();
  const int c0 = tid * 4, c1 = tid * 4 + 1024;
  float4 a0 = *(const float4*)(b_dec + c0);
  float4 a1 = *(const float4*)(b_dec + c1);
#pragma unroll 2
  for (int k = 0; k < KTOP; ++k) {
    float v = sv[k];
    const float* wrp = Wd + (size_t)si[k] * D_IN;
    float4 w0 = *(const float4*)(wrp + c0);
    float4 w1 = *(const float4*)(wrp + c1);
    a0.x += v * w0.x; a0.y += v * w0.y; a0.z += v * w0.z; a0.w += v * w0.w;
    a1.x += v * w1.x; a1.y += v * w1.y; a1.z += v * w1.z; a1.w += v * w1.w;
  }
  *(float4*)(out + (size_t)row * D_IN + c0) = a0;
  *(float4*)(out + (size_t)row * D_IN + c1) = a1;
}

// ---------------- launch ----------------
extern "C" void kernel_launch(void* const* d_in, const int* in_sizes, int n_in,
                              void* d_out, int out_size, void* d_ws, size_t ws_size,
                              hipStream_t stream) {
  const float* x     = (const float*)d_in[0];
  const float* W_enc = (const float*)d_in[1];
  const float* b_enc = (const float*)d_in[2];
  const float* W_dec = (const float*)d_in[3];
  const float* b_dec = (const float*)d_in[4];
  float* out = (float*)d_out;
  char* ws = (char*)d_ws;

  const size_t xBytes = (size_t)BATCH * D_IN * 2;      // 33554432
  const size_t wBytes = (size_t)D_IN * D_SAE * 2;      // 67108864
  const size_t tBytes = (size_t)BATCH * KTOP * 4;      // 3276800
  u16* x_hi = (u16*)(ws);
  u16* x_lo = (u16*)(ws + xBytes);
  u16* w_hi = (u16*)(ws + 2 * xBytes);
  u16* w_lo = (u16*)(ws + 2 * xBytes + wBytes);
  float* tvals = (float*)(ws + 2 * xBytes + 2 * wBytes);
  int*   tidx  = (int*)(ws + 2 * xBytes + 2 * wBytes + tBytes);
  float* pre   = (float*)(ws + 2 * xBytes + 2 * wBytes + 2 * tBytes);
  const size_t fixedBytes = 2 * xBytes + 2 * wBytes + 2 * tBytes;

  // adaptive chunk: pre buffer holds R rows of [D_SAE] fp32
  const size_t perRow = (size_t)D_SAE * 4;
  long avail = (long)ws_size - (long)fixedBytes;
  long r = avail / (long)perRow;
  if (r > BATCH) r = BATCH;
  r &= ~127L;                 // multiple of 128
  if (r < 128) r = 128;       // minimal viable chunk
  const int R = (int)r;

  convert_x_kernel<<<(BATCH * D_IN / 4) / 256, 256, 0, stream>>>(x, b_dec, x_hi, x_lo);
  convert_w_kernel<<<dim3(D_SAE / 32, D_IN / 32), dim3(32, 8), 0, stream>>>(W_enc, w_hi, w_lo);

  for (int row0 = 0; row0 < BATCH; row0 += R) {
    int rows = BATCH - row0 < R ? BATCH - row0 : R;
    encode_gemm_kernel<<<dim3(D_SAE / 128, rows / 128), 256, 0, stream>>>(
        x_hi, x_lo, w_hi, w_lo, b_enc, pre, row0);
    topk_kernel<<<rows, 256, 0, stream>>>(pre, tvals, tidx, row0);
  }
  decode_kernel<<<BATCH, 256, 0, stream>>>(tvals, tidx, W_dec, b_dec, out);
}

// Round 5
// 3197.954 us; speedup vs baseline: 2.2606x; 2.2606x over previous
//
#include <hip/hip_runtime.h>
#include <cstdint>
#include <cstddef>

#define D_IN   2048
#define D_SAE  16384
#define KTOP   100
#define BATCH  8192

typedef unsigned short u16;
typedef unsigned int   u32;
typedef _Float16 f16x8 __attribute__((ext_vector_type(8)));
typedef float    f32x4 __attribute__((ext_vector_type(4)));
typedef u32      u32x4 __attribute__((ext_vector_type(4)));

// async global->LDS, 16B per lane; LDS dest must be wave-uniform base
typedef __attribute__((address_space(1))) const void* gas_t;
typedef __attribute__((address_space(3))) void* las_t;
__device__ __forceinline__ void gload16(const void* g, void* l) {
  __builtin_amdgcn_global_load_lds((gas_t)g, (las_t)l, 16, 0, 0);
}

// ---------------- split conversion: x - b_dec -> f16 hi/lo ----------------
__global__ __launch_bounds__(256)
void convert_x_kernel(const float* __restrict__ x, const float* __restrict__ b_dec,
                      u16* __restrict__ x_hi, u16* __restrict__ x_lo) {
  size_t gid = (size_t)blockIdx.x * blockDim.x + threadIdx.x;  // one float4
  size_t base = gid * 4;
  const float4 xv = *(const float4*)(x + base);
  const float4 bd = *(const float4*)(b_dec + (base & (D_IN - 1)));
  float t[4] = {xv.x - bd.x, xv.y - bd.y, xv.z - bd.z, xv.w - bd.w};
  u32 hpack[2], lpack[2];
  u16 h[4], l[4];
#pragma unroll
  for (int i = 0; i < 4; ++i) {
    _Float16 hi = (_Float16)t[i];
    _Float16 lo = (_Float16)(t[i] - (float)hi);
    h[i] = __builtin_bit_cast(u16, hi);
    l[i] = __builtin_bit_cast(u16, lo);
  }
  hpack[0] = (u32)h[0] | ((u32)h[1] << 16); hpack[1] = (u32)h[2] | ((u32)h[3] << 16);
  lpack[0] = (u32)l[0] | ((u32)l[1] << 16); lpack[1] = (u32)l[2] | ((u32)l[3] << 16);
  *(uint2*)(x_hi + base) = make_uint2(hpack[0], hpack[1]);
  *(uint2*)(x_lo + base) = make_uint2(lpack[0], lpack[1]);
}

// ------------- W_enc [K][N] fp32 -> Wt [N][K] f16 hi/lo (transpose) -------------
__global__ __launch_bounds__(256)
void convert_w_kernel(const float* __restrict__ W, u16* __restrict__ wh, u16* __restrict__ wl) {
  __shared__ float tile[32][33];
  const int tx = threadIdx.x, ty = threadIdx.y;       // 32 x 8
  const int n0 = blockIdx.x * 32, k0 = blockIdx.y * 32;
#pragma unroll
  for (int i = 0; i < 4; ++i)
    tile[ty + 8 * i][tx] = W[(size_t)(k0 + ty + 8 * i) * D_SAE + n0 + tx];
  __syncthreads();
#pragma unroll
  for (int i = 0; i < 4; ++i) {
    int nl = ty + 8 * i;
    float v = tile[tx][nl];
    _Float16 hi = (_Float16)v;
    _Float16 lo = (_Float16)(v - (float)hi);
    size_t o = (size_t)(n0 + nl) * D_IN + k0 + tx;
    wh[o] = __builtin_bit_cast(u16, hi);
    wl[o] = __builtin_bit_cast(u16, lo);
  }
}

// ---------------- encode GEMM: pre = relu(x @ W_enc + b_enc) ----------------
// 128x128 tile, BK=32, 4 waves (2x2), f16 split: hi*hi + hi*lo + lo*hi.
// LDS 32 KB linear (global_load_lds lane-order), 2-barrier m97 structure.
// LDS map: mat (0=A_hi,1=A_lo,2=B_hi,3=B_lo) * 8192 + row*64 + slot*16 bytes.
__global__ __launch_bounds__(256, 2)
void encode_gemm_kernel(const u16* __restrict__ x_hi, const u16* __restrict__ x_lo,
                        const u16* __restrict__ w_hi, const u16* __restrict__ w_lo,
                        const float* __restrict__ b_enc,
                        float* __restrict__ pre, int row0, int nwgy) {
  __shared__ char smem[32768] __attribute__((aligned(16)));
  const int tid = threadIdx.x;
  const int lane = tid & 63, wid = tid >> 6;
  const int wr = wid >> 1, wc = wid & 1;
  const int fr = lane & 15, fs = lane >> 4;

  // XCD-aware bijective swizzle (nwg divisible by 8: nwg = 128*nwgy)
  const int nwg = nwgy << 7;
  const int q = nwg >> 3;
  const int bid = blockIdx.x;
  const int swz = (bid & 7) * q + (bid >> 3);
  const int nBlk = (swz & 127) * 128;     // col-panel (fast within an XCD chunk)
  const int mBlk = (swz >> 7) * 128;      // row-panel

  // staging: per matrix tile = 128 rows x 32 f16 = 8KB = 512 x 16B chunks.
  // wave `wid` owns chunks [wid*64, wid*64+64) and [wid*64+256, ...).
  const int c0 = wid * 64 + lane;
  const int c1 = c0 + 256;
  const int r0 = c0 >> 2, s0 = c0 & 3;
  const int r1 = c1 >> 2, s1 = c1 & 3;

  const u16* gAh0 = x_hi + (size_t)(row0 + mBlk + r0) * D_IN + s0 * 8;
  const u16* gAh1 = x_hi + (size_t)(row0 + mBlk + r1) * D_IN + s1 * 8;
  const u16* gAl0 = x_lo + (size_t)(row0 + mBlk + r0) * D_IN + s0 * 8;
  const u16* gAl1 = x_lo + (size_t)(row0 + mBlk + r1) * D_IN + s1 * 8;
  const u16* gBh0 = w_hi + (size_t)(nBlk + r0) * D_IN + s0 * 8;
  const u16* gBh1 = w_hi + (size_t)(nBlk + r1) * D_IN + s1 * 8;
  const u16* gBl0 = w_lo + (size_t)(nBlk + r0) * D_IN + s0 * 8;
  const u16* gBl1 = w_lo + (size_t)(nBlk + r1) * D_IN + s1 * 8;

  // wave-uniform LDS dests (base + lane*16 written by HW)
  char* lAh0 = smem + 0 * 8192 + wid * 1024;
  char* lAh1 = smem + 0 * 8192 + (wid + 4) * 1024;
  char* lAl0 = smem + 1 * 8192 + wid * 1024;
  char* lAl1 = smem + 1 * 8192 + (wid + 4) * 1024;
  char* lBh0 = smem + 2 * 8192 + wid * 1024;
  char* lBh1 = smem + 2 * 8192 + (wid + 4) * 1024;
  char* lBl0 = smem + 3 * 8192 + wid * 1024;
  char* lBl1 = smem + 3 * 8192 + (wid + 4) * 1024;

  int aAddrH[4], aAddrL[4], bAddrH[4], bAddrL[4];
#pragma unroll
  for (int m = 0; m < 4; ++m) {
    int r = wr * 64 + m * 16 + fr;
    aAddrH[m] = 0 * 8192 + r * 64 + fs * 16;
    aAddrL[m] = 1 * 8192 + r * 64 + fs * 16;
  }
#pragma unroll
  for (int n = 0; n < 4; ++n) {
    int r = wc * 64 + n * 16 + fr;
    bAddrH[n] = 2 * 8192 + r * 64 + fs * 16;
    bAddrL[n] = 3 * 8192 + r * 64 + fs * 16;
  }

  f32x4 acc[4][4] = {};

  for (int kt = 0; kt < D_IN / 32; ++kt) {
    const size_t ko = (size_t)kt * 32;
    __syncthreads();                 // previous LDS reads done
    gload16(gAh0 + ko, lAh0);
    gload16(gAh1 + ko, lAh1);
    gload16(gAl0 + ko, lAl0);
    gload16(gAl1 + ko, lAl1);
    gload16(gBh0 + ko, lBh0);
    gload16(gBh1 + ko, lBh1);
    gload16(gBl0 + ko, lBl0);
    gload16(gBl1 + ko, lBl1);
    __syncthreads();                 // compiler drains vmcnt(0) before barrier

    f16x8 ah[4], al[4], bh[4], bl[4];
#pragma unroll
    for (int m = 0; m < 4; ++m) {
      ah[m] = *(const f16x8*)(smem + aAddrH[m]);
      al[m] = *(const f16x8*)(smem + aAddrL[m]);
    }
#pragma unroll
    for (int n = 0; n < 4; ++n) {
      bh[n] = *(const f16x8*)(smem + bAddrH[n]);
      bl[n] = *(const f16x8*)(smem + bAddrL[n]);
    }
#pragma unroll
    for (int m = 0; m < 4; ++m)
#pragma unroll
      for (int n = 0; n < 4; ++n) {
        acc[m][n] = __builtin_amdgcn_mfma_f32_16x16x32_f16(ah[m], bh[n], acc[m][n], 0, 0, 0);
        acc[m][n] = __builtin_amdgcn_mfma_f32_16x16x32_f16(ah[m], bl[n], acc[m][n], 0, 0, 0);
        acc[m][n] = __builtin_amdgcn_mfma_f32_16x16x32_f16(al[m], bh[n], acc[m][n], 0, 0, 0);
      }
  }

  // epilogue: + b_enc, relu, nontemporal store (keep x/w resident in L3)
#pragma unroll
  for (int n = 0; n < 4; ++n) {
    int col = nBlk + wc * 64 + n * 16 + fr;
    float be = b_enc[col];
#pragma unroll
    for (int m = 0; m < 4; ++m) {
      int rowl = mBlk + wr * 64 + m * 16 + fs * 4;
#pragma unroll
      for (int j = 0; j < 4; ++j) {
        float v = acc[m][n][j] + be;
        v = v > 0.f ? v : 0.f;
        __builtin_nontemporal_store(v, &pre[(size_t)(rowl + j) * D_SAE + col]);
      }
    }
  }
}

// ---------------- top-k: per-row 256 threads, values in VGPRs ----------------
__global__ __launch_bounds__(256)
void topk_kernel(const float* __restrict__ pre, float* __restrict__ tvals,
                 int* __restrict__ tidx, int row0) {
  const int row = blockIdx.x;                       // chunk-local
  const int tid = threadIdx.x;
  const int lane = tid & 63, wid = tid >> 6;
  const float* rp = pre + (size_t)row * D_SAE;
  u32x4 u[16];
#pragma unroll
  for (int j = 0; j < 16; ++j)
    u[j] = __builtin_nontemporal_load((const u32x4*)(rp + tid * 4 + j * 1024));

  __shared__ int red[8];   // double-buffered by bit parity -> 1 barrier/bit
  __shared__ int cnt;

  // binary search max thr with count(>= thr) >= KTOP (uint order == float order, vals >= 0)
  u32 thr = 0;
  for (int b = 30; b >= 0; --b) {
    u32 cand = thr | (1u << b);
    int c = 0;
#pragma unroll
    for (int j = 0; j < 16; ++j)
      c += (u[j].x >= cand) + (u[j].y >= cand) + (u[j].z >= cand) + (u[j].w >= cand);
#pragma unroll
    for (int off = 32; off > 0; off >>= 1) c += __shfl_down(c, off);
    int* rb = red + (b & 1) * 4;
    if (lane == 0) rb[wid] = c;
    __syncthreads();
    int tot = rb[0] + rb[1] + rb[2] + rb[3];
    if (tot >= KTOP) thr = cand;
  }

  __syncthreads();
  if (tid == 0) cnt = 0;
  __syncthreads();
  const int rowg = row0 + row;
  float* tv = tvals + (size_t)rowg * KTOP;
  int*   ti = tidx  + (size_t)rowg * KTOP;
  // pass 1: strictly greater (guaranteed <= KTOP-1 of these)
#pragma unroll
  for (int j = 0; j < 16; ++j) {
    u32 vv[4] = {u[j].x, u[j].y, u[j].z, u[j].w};
#pragma unroll
    for (int q = 0; q < 4; ++q) {
      if (vv[q] > thr) {
        int p = atomicAdd(&cnt, 1);
        if (p < KTOP) { tv[p] = __uint_as_float(vv[q]); ti[p] = tid * 4 + j * 1024 + q; }
      }
    }
  }
  __syncthreads();
  // pass 2: equal to threshold fills the remainder
#pragma unroll
  for (int j = 0; j < 16; ++j) {
    u32 vv[4] = {u[j].x, u[j].y, u[j].z, u[j].w};
#pragma unroll
    for (int q = 0; q < 4; ++q) {
      if (vv[q] == thr) {
        int p = atomicAdd(&cnt, 1);
        if (p < KTOP) { tv[p] = __uint_as_float(vv[q]); ti[p] = tid * 4 + j * 1024 + q; }
      }
    }
  }
}

// ---------------- decode: x_hat = sum_k val*W_dec[idx,:] + b_dec ----------------
__global__ __launch_bounds__(256)
void decode_kernel(const float* __restrict__ tvals, const int* __restrict__ tidx,
                   const float* __restrict__ Wd, const float* __restrict__ b_dec,
                   float* __restrict__ out) {
  const int row = blockIdx.x;
  const int tid = threadIdx.x;
  __shared__ float sv[KTOP];
  __shared__ int   si[KTOP];
  if (tid < KTOP) {
    sv[tid] = tvals[(size_t)row * KTOP + tid];
    si[tid] = tidx[(size_t)row * KTOP + tid];
  }
  __syncthreads();
  const int c0 = tid * 4, c1 = tid * 4 + 1024;
  float4 a0 = *(const float4*)(b_dec + c0);
  float4 a1 = *(const float4*)(b_dec + c1);
#pragma unroll 4
  for (int k = 0; k < KTOP; ++k) {
    float v = sv[k];
    const float* wrp = Wd + (size_t)si[k] * D_IN;
    float4 w0 = *(const float4*)(wrp + c0);
    float4 w1 = *(const float4*)(wrp + c1);
    a0.x += v * w0.x; a0.y += v * w0.y; a0.z += v * w0.z; a0.w += v * w0.w;
    a1.x += v * w1.x; a1.y += v * w1.y; a1.z += v * w1.z; a1.w += v * w1.w;
  }
  *(float4*)(out + (size_t)row * D_IN + c0) = a0;
  *(float4*)(out + (size_t)row * D_IN + c1) = a1;
}

// ---------------- launch ----------------
extern "C" void kernel_launch(void* const* d_in, const int* in_sizes, int n_in,
                              void* d_out, int out_size, void* d_ws, size_t ws_size,
                              hipStream_t stream) {
  const float* x     = (const float*)d_in[0];
  const float* W_enc = (const float*)d_in[1];
  const float* b_enc = (const float*)d_in[2];
  const float* W_dec = (const float*)d_in[3];
  const float* b_dec = (const float*)d_in[4];
  float* out = (float*)d_out;
  char* ws = (char*)d_ws;

  const size_t xBytes = (size_t)BATCH * D_IN * 2;      // 32 MiB
  const size_t wBytes = (size_t)D_IN * D_SAE * 2;      // 64 MiB
  const size_t tBytes = (size_t)BATCH * KTOP * 4;      // 3.125 MiB
  u16* x_hi = (u16*)(ws);
  u16* x_lo = (u16*)(ws + xBytes);
  u16* w_hi = (u16*)(ws + 2 * xBytes);
  u16* w_lo = (u16*)(ws + 2 * xBytes + wBytes);
  float* tvals = (float*)(ws + 2 * xBytes + 2 * wBytes);
  int*   tidx  = (int*)(ws + 2 * xBytes + 2 * wBytes + tBytes);
  float* pre   = (float*)(ws + 2 * xBytes + 2 * wBytes + 2 * tBytes);
  const size_t fixedBytes = 2 * xBytes + 2 * wBytes + 2 * tBytes;

  // adaptive chunk: pre buffer holds R rows of [D_SAE] fp32
  const size_t perRow = (size_t)D_SAE * 4;
  long avail = (long)ws_size - (long)fixedBytes;
  long r = avail / (long)perRow;
  if (r > BATCH) r = BATCH;
  r &= ~127L;                 // multiple of 128
  if (r < 128) r = 128;       // minimal viable chunk
  const int R = (int)r;

  convert_x_kernel<<<(BATCH * D_IN / 4) / 256, 256, 0, stream>>>(x, b_dec, x_hi, x_lo);
  convert_w_kernel<<<dim3(D_SAE / 32, D_IN / 32), dim3(32, 8), 0, stream>>>(W_enc, w_hi, w_lo);

  for (int row0 = 0; row0 < BATCH; row0 += R) {
    int rows = BATCH - row0 < R ? BATCH - row0 : R;
    int nwgy = rows / 128;
    encode_gemm_kernel<<<128 * nwgy, 256, 0, stream>>>(
        x_hi, x_lo, w_hi, w_lo, b_enc, pre, row0, nwgy);
    topk_kernel<<<rows, 256, 0, stream>>>(pre, tvals, tidx, row0);
  }
  decode_kernel<<<BATCH, 256, 0, stream>>>(tvals, tidx, W_dec, b_dec, out);
}